// Round 4
// baseline (1120.101 us; speedup 1.0000x reference)
//
#include <hip/hip_runtime.h>

// ============================================================================
// ViT encoder (patch embed + windowed block + global block) on gfx950.
// Round 4: flash LDS de-conflict (stride 72 pad, Gw hoist, P aliases GW,
//          3 blocks/CU) + mgemm global_load_lds (16B async staging).
// ============================================================================

using u16 = unsigned short;
using u32 = unsigned int;
using short8  = __attribute__((ext_vector_type(8))) short;
using floatx4 = __attribute__((ext_vector_type(4))) float;

__device__ __forceinline__ float bfu2f(u16 u) { return __builtin_bit_cast(float, (u32)u << 16); }
__device__ __forceinline__ u16   f2bfu(float f) {
  u32 u = __builtin_bit_cast(u32, f);
  return (u16)((u + 0x7fffu + ((u >> 16) & 1u)) >> 16);   // RNE
}
#define DIV14(x) (((x) * 4682) >> 16)   // exact floor(x/14) for 0<=x<256

// async global->LDS, 16B per lane; LDS dest = wave-uniform base + lane*16
__device__ __forceinline__ void gld_lds16(const u16* g, u16* l) {
  __builtin_amdgcn_global_load_lds(
      (const __attribute__((address_space(1))) u32*)g,
      (__attribute__((address_space(3))) u32*)l, 16, 0, 0);
}

// ---------------------------------------------------------------------------
// dtype detector: FLAG=1 => bf16 tensors, FLAG=0 => fp32.
// ---------------------------------------------------------------------------
__global__ __launch_bounds__(256) void detect_k(const u16* __restrict__ x, int* __restrict__ flag)
{
  __shared__ int tot;
  if (threadIdx.x == 0) tot = 0;
  __syncthreads();
  int cnt = 0;
  for (int i = threadIdx.x; i < 4096; i += 256) {
    int e = (x[2 * i] >> 7) & 0xFF;
    cnt += (e >= 100 && e <= 134) ? 1 : 0;
  }
  atomicAdd(&tot, cnt);
  __syncthreads();
  if (threadIdx.x == 0) *flag = (tot >= 2458) ? 1 : 0;
}

// ---------------------------------------------------------------------------
// small-param conversion -> bf16 mirror
// ---------------------------------------------------------------------------
struct CvtEnt { const void* src; int n; int dstoff; };
struct CvtArgs { CvtEnt e[24]; int cnt; };

__global__ __launch_bounds__(256) void tobf_multi_k(CvtArgs a, u16* __restrict__ dst,
                                                    const int* __restrict__ flag)
{
  int gid = blockIdx.x * 256 + threadIdx.x;
  bool isbf = (*flag != 0);
  for (int t = 0; t < a.cnt; ++t)
    if (gid < a.e[t].n)
      dst[a.e[t].dstoff + gid] = isbf ? ((const u16*)a.e[t].src)[gid]
                                      : f2bfu(((const float*)a.e[t].src)[gid]);
}

__global__ __launch_bounds__(256) void tobf4_k(const void* __restrict__ src, u16* __restrict__ dst,
                                               int n4, const int* __restrict__ flag)
{
  int i = blockIdx.x * 256 + threadIdx.x;
  if (i >= n4) return;
  ushort4 o;
  if (*flag) o = ((const ushort4*)src)[i];
  else {
    float4 f = ((const float4*)src)[i];
    o.x = f2bfu(f.x); o.y = f2bfu(f.y); o.z = f2bfu(f.z); o.w = f2bfu(f.w);
  }
  ((ushort4*)dst)[i] = o;
}

// ---------------------------------------------------------------------------
// Weight convert + transpose: W[K][N] -> Wt[N][K] bf16. 64x64 LDS tiles.
// ---------------------------------------------------------------------------
__global__ __launch_bounds__(256) void tobfT_k(const void* __restrict__ src, u16* __restrict__ dst,
                                               int K, int N, const int* __restrict__ flag)
{
  __shared__ u16 t[64][65];
  const int n0 = blockIdx.x * 64, k0 = blockIdx.y * 64;
  const int r = threadIdx.x >> 2, c = (threadIdx.x & 3) * 16;
  if (*flag) {
    const u16* s = (const u16*)src + (size_t)(k0 + r) * N + n0 + c;
    union { uint4 v[2]; u16 e[16]; } u;
    u.v[0] = *(const uint4*)s; u.v[1] = *(const uint4*)(s + 8);
    #pragma unroll
    for (int j = 0; j < 16; ++j) t[c + j][r] = u.e[j];
  } else {
    const float* s = (const float*)src + (size_t)(k0 + r) * N + n0 + c;
    #pragma unroll
    for (int j = 0; j < 16; ++j) t[c + j][r] = f2bfu(s[j]);
  }
  __syncthreads();
  union { uint4 v[2]; u16 e[16]; } o;
  #pragma unroll
  for (int j = 0; j < 16; ++j) o.e[j] = t[r][c + j];
  u16* d = dst + (size_t)(n0 + r) * K + k0 + c;
  *(uint4*)d = o.v[0]; *(uint4*)(d + 8) = o.v[1];
}

// ---------------------------------------------------------------------------
// im2col for the 16x16/stride-16 patch embed
// ---------------------------------------------------------------------------
__global__ __launch_bounds__(256) void im2col_k(const void* __restrict__ xv, u16* __restrict__ a,
                                                const int* __restrict__ flag)
{
  int t = blockIdx.x, tid = threadIdx.x;
  int py = t >> 6, px = t & 63;
  int ky = tid >> 4, kx = tid & 15;
  size_t src = (size_t)(py * 16 + ky) * 1024 + px * 16 + kx;
  u16 v0, v1, v2;
  if (*flag) {
    const u16* x = (const u16*)xv;
    v0 = x[src]; v1 = x[src + 1048576]; v2 = x[src + 2097152];
  } else {
    const float* x = (const float*)xv;
    v0 = f2bfu(x[src]); v1 = f2bfu(x[src + 1048576]); v2 = f2bfu(x[src + 2097152]);
  }
  size_t dst = (size_t)t * 768 + tid * 3;
  a[dst] = v0; a[dst + 1] = v1; a[dst + 2] = v2;
}

// ---------------------------------------------------------------------------
// LayerNorm over C=768, f32 in -> bf16 out
// ---------------------------------------------------------------------------
__global__ __launch_bounds__(256) void ln_k(const float* __restrict__ x,
                                            const u16* __restrict__ g,
                                            const u16* __restrict__ b,
                                            u16* __restrict__ y)
{
  const int t = blockIdx.x, tid = threadIdx.x;
  const float* xp = x + (size_t)t * 768;
  float v0 = xp[tid], v1 = xp[tid + 256], v2 = xp[tid + 512];
  float s = v0 + v1 + v2;
  float q = v0 * v0 + v1 * v1 + v2 * v2;
  #pragma unroll
  for (int off = 32; off; off >>= 1) { s += __shfl_xor(s, off); q += __shfl_xor(q, off); }
  __shared__ float red[8];
  int wid = tid >> 6, lane = tid & 63;
  if (lane == 0) { red[wid] = s; red[4 + wid] = q; }
  __syncthreads();
  s = red[0] + red[1] + red[2] + red[3];
  q = red[4] + red[5] + red[6] + red[7];
  float mean = s * (1.f / 768.f);
  float var  = q * (1.f / 768.f) - mean * mean;
  float rstd = rsqrtf(var + 1e-5f);
  u16* yp = y + (size_t)t * 768;
  yp[tid]       = f2bfu((v0 - mean) * rstd * bfu2f(g[tid])       + bfu2f(b[tid]));
  yp[tid + 256] = f2bfu((v1 - mean) * rstd * bfu2f(g[tid + 256]) + bfu2f(b[tid + 256]));
  yp[tid + 512] = f2bfu((v2 - mean) * rstd * bfu2f(g[tid + 512]) + bfu2f(b[tid + 512]));
}

// ---------------------------------------------------------------------------
// Window partition 64x64 -> 25 windows of 14x14 zero-padded
// ---------------------------------------------------------------------------
__global__ __launch_bounds__(256) void win_part_k(const u16* __restrict__ ln, u16* __restrict__ w)
{
  int vid = blockIdx.x * 256 + threadIdx.x;
  if (vid >= 470400) return;
  size_t idx = (size_t)vid * 8;
  int c = (int)(idx % 768);
  int r = (int)(idx / 768);
  int win = r / 196, tok = r - win * 196;
  int gy = (win / 5) * 14 + tok / 14;
  int gx = (win % 5) * 14 + tok % 14;
  uint4 v = make_uint4(0, 0, 0, 0);
  if (gy < 64 && gx < 64)
    v = *(const uint4*)(ln + ((size_t)(gy * 64 + gx) * 768 + c));
  *(uint4*)(w + idx) = v;
}

// ---------------------------------------------------------------------------
// MFMA GEMM with global_load_lds staging.
// C = A(MxK) * Bt(NxK)^T + bias, fused epilogues. 128xBN tile, BK=32.
// ---------------------------------------------------------------------------
enum { MODE_FEAT = 0, MODE_QKV = 1, MODE_RES = 2, MODE_GELU = 3, MODE_OUT = 4 };

template<int BN>
__global__ __launch_bounds__(256) void mgemm_k(
    const u16* __restrict__ A, const u16* __restrict__ Bt, const u16* __restrict__ bias,
    int M, int N, int K, int mode,
    float* __restrict__ outf, u16* __restrict__ outb,
    const float* __restrict__ res, const u16* __restrict__ pos,
    u16* __restrict__ qb, u16* __restrict__ kb, u16* __restrict__ vt, int TW,
    const int* __restrict__ flagp)
{
  constexpr int NWN = BN / 64, NWM = 4 / NWN;
  constexpr int WTM = 128 / NWM;            // 64 or 32
  constexpr int MS = WTM / 16, NS = 4;
  __shared__ __align__(16) u16 As[128 * 32];
  __shared__ __align__(16) u16 Bs[BN * 32];
  const int tid = threadIdx.x;
  const int wid = tid >> 6, lane = tid & 63;
  const int l15 = lane & 15, quad = lane >> 4;
  const int wm = wid / NWN, wn = wid % NWN;
  const int m0 = blockIdx.y * 128, n0 = blockIdx.x * BN;

  floatx4 acc[MS][NS];
  #pragma unroll
  for (int i = 0; i < MS; ++i)
    #pragma unroll
    for (int j = 0; j < NS; ++j) acc[i][j] = (floatx4){0.f, 0.f, 0.f, 0.f};

  // staging: per wave, A rows [wid*32, wid*32+32), 16 rows per call (lane>>2),
  // 8 u16 per lane (lane&3)*8. LDS dest is contiguous: base + lane*16B.
  const int sr = lane >> 2, sc = (lane & 3) * 8;
  const u16* ag0 = A + (size_t)min(m0 + wid * 32 + sr,      M - 1) * K + sc;
  const u16* ag1 = A + (size_t)min(m0 + wid * 32 + 16 + sr, M - 1) * K + sc;
  u16* al0 = &As[(wid * 32) * 32];
  u16* al1 = &As[(wid * 32 + 16) * 32];
  const u16 *bg0, *bg1;
  u16 *bl0, *bl1;
  if constexpr (BN == 128) {
    bg0 = Bt + (size_t)(n0 + wid * 32 + sr) * K + sc;
    bg1 = Bt + (size_t)(n0 + wid * 32 + 16 + sr) * K + sc;
    bl0 = &Bs[(wid * 32) * 32];
    bl1 = &Bs[(wid * 32 + 16) * 32];
  } else {
    bg0 = Bt + (size_t)(n0 + wid * 16 + sr) * K + sc;
    bl0 = &Bs[(wid * 16) * 32];
    bg1 = nullptr; bl1 = nullptr;
  }

  for (int k0 = 0; k0 < K; k0 += 32) {
    __syncthreads();                       // prior LDS reads complete
    gld_lds16(ag0 + k0, al0);
    gld_lds16(ag1 + k0, al1);
    gld_lds16(bg0 + k0, bl0);
    if constexpr (BN == 128) gld_lds16(bg1 + k0, bl1);
    __builtin_amdgcn_s_waitcnt(0x3f70);    // vmcnt(0)
    __syncthreads();
    short8 af[MS], bf[NS];
    #pragma unroll
    for (int ms = 0; ms < MS; ++ms)
      af[ms] = *(const short8*)&As[(wm * WTM + ms * 16 + l15) * 32 + quad * 8];
    #pragma unroll
    for (int ns = 0; ns < NS; ++ns)
      bf[ns] = *(const short8*)&Bs[(wn * 64 + ns * 16 + l15) * 32 + quad * 8];
    #pragma unroll
    for (int ms = 0; ms < MS; ++ms)
      #pragma unroll
      for (int ns = 0; ns < NS; ++ns)
        acc[ms][ns] = __builtin_amdgcn_mfma_f32_16x16x32_bf16(af[ms], bf[ns], acc[ms][ns], 0, 0, 0);
  }

  const bool outbf = (mode == MODE_OUT) ? (*flagp != 0) : false;
  #pragma unroll
  for (int ms = 0; ms < MS; ++ms) {
    const int gmb = m0 + wm * WTM + ms * 16 + quad * 4;
    #pragma unroll
    for (int ns = 0; ns < NS; ++ns) {
      const int gn = n0 + wn * 64 + ns * 16 + l15;
      const float bb = bfu2f(bias[gn]);
      if (mode == MODE_QKV) {
        const int s = gn / 768, nn = gn - s * 768, h = nn >> 6, d = nn & 63;
        #pragma unroll
        for (int r = 0; r < 4; ++r) {
          int gm = gmb + r; if (gm >= M) continue;
          float v = acc[ms][ns][r] + bb;
          int b = gm / TW, tok = gm - b * TW;
          size_t bh = (size_t)(b * 12 + h);
          if (s == 0)      qb[(bh * TW + tok) * 64 + d] = f2bfu(v);
          else if (s == 1) kb[(bh * TW + tok) * 64 + d] = f2bfu(v);
          else             vt[(bh * 64 + d) * TW + tok] = f2bfu(v);
        }
      } else {
        #pragma unroll
        for (int r = 0; r < 4; ++r) {
          int gm = gmb + r; if (gm >= M) continue;
          size_t o = (size_t)gm * N + gn;
          float v = acc[ms][ns][r] + bb;
          if (mode == MODE_FEAT)      outf[o] = v + bfu2f(pos[o]);
          else if (mode == MODE_RES)  outf[o] = v + res[o];
          else if (mode == MODE_GELU) outb[o] = f2bfu(0.5f * v * (1.f + erff(v * 0.70710678f)));
          else {
            float ov = v + res[o];
            if (outbf) outb[o] = f2bfu(ov);
            else       outf[o] = ov;
          }
        }
      }
    }
  }
}

// ---------------------------------------------------------------------------
// MFMA flash attention. LDS strides padded to 72 u16 (2-way bank alias = free);
// GH/GW gather strides 66/130 (WIN: 34). Global block hoists Gw into regs;
// P region aliases the dead GW region (global) -> 52.7 KB => 3 blocks/CU.
// ---------------------------------------------------------------------------
template<int NT, int TD, bool WIN>
__global__ __launch_bounds__(256) void flash_k(
    const u16* __restrict__ qb, const u16* __restrict__ kb, const u16* __restrict__ vt,
    const u16* __restrict__ relh, const u16* __restrict__ relw,
    u16* __restrict__ outb)
{
  constexpr int NTAB = 2 * TD - 1;
  constexpr int KT = (NT + 63) >> 6;
  constexpr int TS = 72;                         // padded tile stride (u16)
  constexpr int GHS = WIN ? 34 : 66;
  constexpr int GWS = WIN ? 34 : 130;
  constexpr int GHN = WIN ? 32 : 64;             // gather-table width
  constexpr int GWN = WIN ? 32 : 128;
  constexpr int Q0 = 0, K0 = 64 * TS, V0 = 2 * 64 * TS, GH0 = 3 * 64 * TS;
  constexpr int GW0 = GH0 + 64 * GHS;
  constexpr int P0 = WIN ? (GW0 + 64 * GWS) : GW0;   // P aliases GW (global)
  constexpr int TOT = WIN ? (P0 + 64 * TS) : (GW0 + 64 * GWS);
  constexpr int RB0 = K0;                        // rel staging aliases K tile
  __shared__ __align__(16) u16 lds[TOT];

  const int tid = threadIdx.x, wid = tid >> 6, lane = tid & 63;
  const int l15 = lane & 15, quad = lane >> 4;
  const int qt = blockIdx.x, bh = blockIdx.y;
  const int q0 = qt * 64;
  const size_t kvbase = (size_t)bh * NT * 64;
  const size_t vbase  = (size_t)bh * 64 * NT;

  // ---- stage Q tile (row-clamped) ----
  {
    const int r = tid >> 2, c = (tid & 3) << 4;
    const int tok = min(q0 + r, NT - 1);
    const uint4* p = (const uint4*)(qb + kvbase + (size_t)tok * 64 + c);
    *(uint4*)&lds[Q0 + r * TS + c]     = p[0];
    *(uint4*)&lds[Q0 + r * TS + c + 8] = p[1];
  }

  // ---- G phase ----
  auto stageRB = [&](const u16* tab, int rowoff, int maxrow) {
    const int r = tid >> 2, c = (tid & 3) << 4;
    const int tr = min(rowoff + r, maxrow);
    const uint4* p = (const uint4*)(tab + (size_t)tr * 64 + c);
    *(uint4*)&lds[RB0 + r * TS + c]     = p[0];
    *(uint4*)&lds[RB0 + r * TS + c + 8] = p[1];
  };
  auto gpass = [&](int ncols, int gbase, int gstride, int co) {
    for (int ns = 0; ns < ncols / 16; ++ns) {
      floatx4 g = (floatx4){0.f, 0.f, 0.f, 0.f};
      #pragma unroll
      for (int ks = 0; ks < 2; ++ks) {
        short8 a = *(const short8*)&lds[Q0 + (wid * 16 + l15) * TS + ks * 32 + quad * 8];
        short8 b = *(const short8*)&lds[RB0 + (ns * 16 + l15) * TS + ks * 32 + quad * 8];
        g = __builtin_amdgcn_mfma_f32_16x16x32_bf16(a, b, g, 0, 0, 0);
      }
      #pragma unroll
      for (int r = 0; r < 4; ++r)
        lds[gbase + (wid * 16 + quad * 4 + r) * gstride + co + ns * 16 + l15] = f2bfu(g[r]);
    }
  };

  stageRB(relh, WIN ? 0 : qt, NTAB - 1);
  __syncthreads();
  gpass(GHN, GH0, GHS, 0);
  __syncthreads();
  stageRB(relw, 0, NTAB - 1);
  __syncthreads();
  gpass(GWN > 64 ? 64 : GWN, GW0, GWS, 0);
  __syncthreads();
  if constexpr (GWN > 64) {
    stageRB(relw, 64, NTAB - 1);
    __syncthreads();
    gpass(64, GW0, GWS, 64);
    __syncthreads();
  }

  // ---- hoist Gw into registers (global block: iw = tr-cj+63, kt-invariant) ----
  float gwv[4][4];
  if constexpr (!WIN) {
    #pragma unroll
    for (int r = 0; r < 4; ++r) {
      const int tr = wid * 16 + quad * 4 + r;
      #pragma unroll
      for (int ns = 0; ns < 4; ++ns) {
        const int cj = ns * 16 + l15;
        gwv[ns][r] = bfu2f(lds[GW0 + tr * GWS + (tr - cj + 63)]);
      }
    }
  }

  // ---- online-softmax state ----
  float mI[4], lI[4];
  floatx4 Oacc[4];
  #pragma unroll
  for (int r = 0; r < 4; ++r) { mI[r] = -3e38f; lI[r] = 0.f; }
  #pragma unroll
  for (int d = 0; d < 4; ++d) Oacc[d] = (floatx4){0.f, 0.f, 0.f, 0.f};

  // ---- K loop ----
  for (int kt = 0; kt < KT; ++kt) {
    __syncthreads();           // prior tile's LDS reads (and gwv reads) done
    {
      const int r = tid >> 2, c = (tid & 3) << 4;
      const int key = min(kt * 64 + r, NT - 1);
      const uint4* p = (const uint4*)(kb + kvbase + (size_t)key * 64 + c);
      *(uint4*)&lds[K0 + r * TS + c]     = p[0];
      *(uint4*)&lds[K0 + r * TS + c + 8] = p[1];
    }
    if constexpr (NT % 64 == 0) {
      const int d = tid >> 2, c = (tid & 3) << 4;
      const uint4* p = (const uint4*)(vt + vbase + (size_t)d * NT + kt * 64 + c);
      *(uint4*)&lds[V0 + d * TS + c]     = p[0];
      *(uint4*)&lds[V0 + d * TS + c + 8] = p[1];
    } else {
      const int d = tid >> 2, c = (tid & 3) << 4;
      #pragma unroll
      for (int j = 0; j < 16; ++j) {
        int key = min(kt * 64 + c + j, NT - 1);
        lds[V0 + d * TS + c + j] = vt[vbase + (size_t)d * NT + key];
      }
    }
    __syncthreads();

    // QK^T
    floatx4 sacc[4];
    #pragma unroll
    for (int ns = 0; ns < 4; ++ns) sacc[ns] = (floatx4){0.f, 0.f, 0.f, 0.f};
    #pragma unroll
    for (int ks = 0; ks < 2; ++ks) {
      short8 a = *(const short8*)&lds[Q0 + (wid * 16 + l15) * TS + ks * 32 + quad * 8];
      #pragma unroll
      for (int ns = 0; ns < 4; ++ns) {
        short8 b = *(const short8*)&lds[K0 + (ns * 16 + l15) * TS + ks * 32 + quad * 8];
        sacc[ns] = __builtin_amdgcn_mfma_f32_16x16x32_bf16(a, b, sacc[ns], 0, 0, 0);
      }
    }

    // scale + rel bias + mask
    float sv[4][4];
    #pragma unroll
    for (int r = 0; r < 4; ++r) {
      const int tr = wid * 16 + quad * 4 + r;
      if constexpr (!WIN) {
        const float ghv = bfu2f(lds[GH0 + tr * GHS + (63 - kt)]);
        #pragma unroll
        for (int ns = 0; ns < 4; ++ns)
          sv[ns][r] = 0.125f * sacc[ns][r] + ghv + gwv[ns][r];
      } else {
        const int tok = q0 + tr;
        const int qy = DIV14(tok), qx = tok - 14 * qy;
        #pragma unroll
        for (int ns = 0; ns < 4; ++ns) {
          const int j = kt * 64 + ns * 16 + l15;
          const int ky = DIV14(j), kx = j - 14 * ky;
          int ih = qy - ky + 13; ih = max(0, min(ih, GHN - 1));
          int iw = qx - kx + 13; iw = max(0, min(iw, GWN - 1));
          float s = 0.125f * sacc[ns][r] + bfu2f(lds[GH0 + tr * GHS + ih])
                                        + bfu2f(lds[GW0 + tr * GWS + iw]);
          sv[ns][r] = (j < NT) ? s : -1e30f;
        }
      }
    }

    // online softmax
    #pragma unroll
    for (int r = 0; r < 4; ++r) {
      float rm = fmaxf(fmaxf(sv[0][r], sv[1][r]), fmaxf(sv[2][r], sv[3][r]));
      #pragma unroll
      for (int off = 1; off < 16; off <<= 1) rm = fmaxf(rm, __shfl_xor(rm, off));
      const float mn = fmaxf(mI[r], rm);
      const float al = __expf(mI[r] - mn);
      mI[r] = mn;
      float rs = 0.f;
      #pragma unroll
      for (int ns = 0; ns < 4; ++ns) {
        float p = __expf(sv[ns][r] - mn);
        rs += p;
        lds[P0 + (wid * 16 + quad * 4 + r) * TS + ns * 16 + l15] = f2bfu(p);
      }
      #pragma unroll
      for (int off = 1; off < 16; off <<= 1) rs += __shfl_xor(rs, off);
      lI[r] = lI[r] * al + rs;
      #pragma unroll
      for (int d = 0; d < 4; ++d) Oacc[d][r] *= al;
    }

    // PV
    #pragma unroll
    for (int ks = 0; ks < 2; ++ks) {
      short8 a = *(const short8*)&lds[P0 + (wid * 16 + l15) * TS + ks * 32 + quad * 8];
      #pragma unroll
      for (int d = 0; d < 4; ++d) {
        short8 b = *(const short8*)&lds[V0 + (d * 16 + l15) * TS + ks * 32 + quad * 8];
        Oacc[d] = __builtin_amdgcn_mfma_f32_16x16x32_bf16(a, b, Oacc[d], 0, 0, 0);
      }
    }
  }

  // ---- output ----
  #pragma unroll
  for (int r = 0; r < 4; ++r) {
    const int tr = wid * 16 + quad * 4 + r;
    const float rinv = 1.f / lI[r];
    const int tok = q0 + tr;
    if constexpr (WIN) {
      if (tok >= NT) continue;
      const int win = bh / 12, h = bh - win * 12;
      const int ty = DIV14(tok), tx = tok - 14 * ty;
      const int gy = (win / 5) * 14 + ty, gx = (win % 5) * 14 + tx;
      if (gy >= 64 || gx >= 64) continue;
      u16* op = outb + (size_t)(gy * 64 + gx) * 768 + h * 64;
      #pragma unroll
      for (int d = 0; d < 4; ++d) op[d * 16 + l15] = f2bfu(Oacc[d][r] * rinv);
    } else {
      u16* op = outb + (size_t)tok * 768 + bh * 64;
      #pragma unroll
      for (int d = 0; d < 4; ++d) op[d * 16 + l15] = f2bfu(Oacc[d][r] * rinv);
    }
  }
}

// ---------------------------------------------------------------------------
extern "C" void kernel_launch(void* const* d_in, const int* in_sizes, int n_in,
                              void* d_out, int out_size, void* d_ws, size_t ws_size,
                              hipStream_t stream)
{
  const void* x      = d_in[0];
  const void* patchw = d_in[1];
  const void* patchb = d_in[2];
  const void* pos    = d_in[3];
  const void *ln1g1 = d_in[4],  *ln1b1 = d_in[5];
  const void *qkvw1 = d_in[6],  *qkvb1 = d_in[7];
  const void *projw1= d_in[8],  *projb1= d_in[9];
  const void *relh1 = d_in[10], *relw1 = d_in[11];
  const void *ln2g1 = d_in[12], *ln2b1 = d_in[13];
  const void *mw11  = d_in[14], *mb11  = d_in[15];
  const void *mw21  = d_in[16], *mb21  = d_in[17];
  const void *ln1g2 = d_in[18], *ln1b2 = d_in[19];
  const void *qkvw2 = d_in[20], *qkvb2 = d_in[21];
  const void *projw2= d_in[22], *projb2= d_in[23];
  const void *relh2 = d_in[24], *relw2 = d_in[25];
  const void *ln2g2 = d_in[26], *ln2b2 = d_in[27];
  const void *mw12  = d_in[28], *mb12  = d_in[29];
  const void *mw22  = d_in[30], *mb22  = d_in[31];

  char* w = (char*)d_ws;
  int*   FLAG = (int*)w;  w += 64;
  float* R0 = (float*)w;  w += 12582912;
  float* R1 = (float*)w;  w += 12582912;
  u16*   B0 = (u16*)w;    w += 6291456;
  u16*   Wb = (u16*)w;    w += 7526400;
  u16*   QB = (u16*)w;    w += 7526400;   // [bh][tok][64]
  u16*   KB = (u16*)w;    w += 7526400;   // [bh][tok][64]
  u16*   VT = (u16*)w;    w += 7526400;   // [bh][d][tok]
  u16*   Hb = (u16*)w;    w += 25165824;
  u16*   WA = (u16*)w;    w += 14155776;  // transposed weight arena
  u16*   POSb = (u16*)w;  w += 6291456;
  u16*   PRM = (u16*)w;   w += 106560;
  u16*   Ap = Hb;

  constexpr int WA_QKV = 0, WA_PROJ = 1769472, WA_M1 = 2359296, WA_M2 = 4718592;
  constexpr int PRM_PATCHB = 0, PB1 = 768, PBLK = 26240, PB2 = 768 + PBLK;
  constexpr int O_QKVB = 0, O_PROJB = 2304, O_MB1 = 3072, O_MB2 = 6144,
                O_LN1G = 6912, O_LN1B = 7680, O_LN2G = 8448, O_LN2B = 9216,
                O_RELH = 9984, O_RELW = 18112;

  detect_k<<<1, 256, 0, stream>>>((const u16*)x, FLAG);
  CvtArgs ca; int kk = 0;
  auto add = [&](const void* s, int n, int off) { ca.e[kk].src = s; ca.e[kk].n = n; ca.e[kk].dstoff = off; ++kk; };
  add(patchb, 768, PRM_PATCHB);
  add(qkvb1, 2304, PB1 + O_QKVB); add(projb1, 768, PB1 + O_PROJB);
  add(mb11, 3072, PB1 + O_MB1);   add(mb21, 768, PB1 + O_MB2);
  add(ln1g1, 768, PB1 + O_LN1G);  add(ln1b1, 768, PB1 + O_LN1B);
  add(ln2g1, 768, PB1 + O_LN2G);  add(ln2b1, 768, PB1 + O_LN2B);
  add(relh1, 27 * 64, PB1 + O_RELH); add(relw1, 27 * 64, PB1 + O_RELW);
  add(qkvb2, 2304, PB2 + O_QKVB); add(projb2, 768, PB2 + O_PROJB);
  add(mb12, 3072, PB2 + O_MB1);   add(mb22, 768, PB2 + O_MB2);
  add(ln1g2, 768, PB2 + O_LN1G);  add(ln1b2, 768, PB2 + O_LN1B);
  add(ln2g2, 768, PB2 + O_LN2G);  add(ln2b2, 768, PB2 + O_LN2B);
  add(relh2, 127 * 64, PB2 + O_RELH); add(relw2, 127 * 64, PB2 + O_RELW);
  ca.cnt = kk;
  tobf_multi_k<<<32, 256, 0, stream>>>(ca, PRM, FLAG);
  tobf4_k<<<3072, 256, 0, stream>>>(pos, POSb, 786432, FLAG);

  // ---- patch embed ----
  tobfT_k<<<dim3(12, 12), 256, 0, stream>>>(patchw, WA + WA_M1, 768, 768, FLAG);
  im2col_k<<<4096, 256, 0, stream>>>(x, Ap, FLAG);
  mgemm_k<64><<<dim3(12, 32), 256, 0, stream>>>(Ap, WA + WA_M1, PRM + PRM_PATCHB,
      4096, 768, 768, MODE_FEAT, R0, nullptr, nullptr, POSb, nullptr, nullptr, nullptr, 0, FLAG);

  // ---- block 1 weights ----
  tobfT_k<<<dim3(36, 12), 256, 0, stream>>>(qkvw1, WA + WA_QKV, 768, 2304, FLAG);
  tobfT_k<<<dim3(12, 12), 256, 0, stream>>>(projw1, WA + WA_PROJ, 768, 768, FLAG);
  tobfT_k<<<dim3(48, 12), 256, 0, stream>>>(mw11, WA + WA_M1, 768, 3072, FLAG);
  tobfT_k<<<dim3(12, 48), 256, 0, stream>>>(mw21, WA + WA_M2, 3072, 768, FLAG);

  // ---- block 1 (windowed) ----
  ln_k<<<4096, 256, 0, stream>>>(R0, PRM + PB1 + O_LN1G, PRM + PB1 + O_LN1B, B0);
  win_part_k<<<1838, 256, 0, stream>>>(B0, Wb);
  mgemm_k<128><<<dim3(18, 39), 256, 0, stream>>>(Wb, WA + WA_QKV, PRM + PB1 + O_QKVB,
      4900, 2304, 768, MODE_QKV, nullptr, nullptr, nullptr, nullptr, QB, KB, VT, 196, FLAG);
  flash_k<196, 14, true><<<dim3(4, 300), 256, 0, stream>>>(QB, KB, VT,
      PRM + PB1 + O_RELH, PRM + PB1 + O_RELW, B0);
  mgemm_k<64><<<dim3(12, 32), 256, 0, stream>>>(B0, WA + WA_PROJ, PRM + PB1 + O_PROJB,
      4096, 768, 768, MODE_RES, R1, nullptr, R0, nullptr, nullptr, nullptr, nullptr, 0, FLAG);
  ln_k<<<4096, 256, 0, stream>>>(R1, PRM + PB1 + O_LN2G, PRM + PB1 + O_LN2B, B0);
  mgemm_k<128><<<dim3(24, 32), 256, 0, stream>>>(B0, WA + WA_M1, PRM + PB1 + O_MB1,
      4096, 3072, 768, MODE_GELU, nullptr, Hb, nullptr, nullptr, nullptr, nullptr, nullptr, 0, FLAG);
  mgemm_k<64><<<dim3(12, 32), 256, 0, stream>>>(Hb, WA + WA_M2, PRM + PB1 + O_MB2,
      4096, 768, 3072, MODE_RES, R0, nullptr, R1, nullptr, nullptr, nullptr, nullptr, 0, FLAG);

  // ---- block 2 weights ----
  tobfT_k<<<dim3(36, 12), 256, 0, stream>>>(qkvw2, WA + WA_QKV, 768, 2304, FLAG);
  tobfT_k<<<dim3(12, 12), 256, 0, stream>>>(projw2, WA + WA_PROJ, 768, 768, FLAG);
  tobfT_k<<<dim3(48, 12), 256, 0, stream>>>(mw12, WA + WA_M1, 768, 3072, FLAG);
  tobfT_k<<<dim3(12, 48), 256, 0, stream>>>(mw22, WA + WA_M2, 3072, 768, FLAG);

  // ---- block 2 (global) ----
  ln_k<<<4096, 256, 0, stream>>>(R0, PRM + PB2 + O_LN1G, PRM + PB2 + O_LN1B, B0);
  mgemm_k<128><<<dim3(18, 32), 256, 0, stream>>>(B0, WA + WA_QKV, PRM + PB2 + O_QKVB,
      4096, 2304, 768, MODE_QKV, nullptr, nullptr, nullptr, nullptr, QB, KB, VT, 4096, FLAG);
  flash_k<4096, 64, false><<<dim3(64, 12), 256, 0, stream>>>(QB, KB, VT,
      PRM + PB2 + O_RELH, PRM + PB2 + O_RELW, B0);
  mgemm_k<64><<<dim3(12, 32), 256, 0, stream>>>(B0, WA + WA_PROJ, PRM + PB2 + O_PROJB,
      4096, 768, 768, MODE_RES, R1, nullptr, R0, nullptr, nullptr, nullptr, nullptr, 0, FLAG);
  ln_k<<<4096, 256, 0, stream>>>(R1, PRM + PB2 + O_LN2G, PRM + PB2 + O_LN2B, B0);
  mgemm_k<128><<<dim3(24, 32), 256, 0, stream>>>(B0, WA + WA_M1, PRM + PB2 + O_MB1,
      4096, 3072, 768, MODE_GELU, nullptr, Hb, nullptr, nullptr, nullptr, nullptr, nullptr, 0, FLAG);
  mgemm_k<64><<<dim3(12, 32), 256, 0, stream>>>(Hb, WA + WA_M2, PRM + PB2 + O_MB2,
      4096, 768, 3072, MODE_OUT, (float*)d_out, (u16*)d_out, R1, nullptr, nullptr, nullptr, nullptr, 0, FLAG);
}

// Round 6
// 891.454 us; speedup vs baseline: 1.2565x; 1.2565x over previous
//
#include <hip/hip_runtime.h>

// ============================================================================
// ViT encoder (patch embed + windowed block + global block) on gfx950.
// Round 6 (= round 5 with the kb-shadowing compile fix):
//   - mgemm: double-buffered global_load_lds (loads for tile k+1 in flight
//     during tile k's MFMAs; single barrier per K-step)
//   - flash: Q fragment hoisted to VGPRs; P aliases Q region; !WIN GW scratch
//     aliases K region => LDS 52.7 -> 36.1 KB (4 blocks/CU); Gh folded into
//     softmax shift (tile-constant for global block)
// ============================================================================

using u16 = unsigned short;
using u32 = unsigned int;
using short8  = __attribute__((ext_vector_type(8))) short;
using floatx4 = __attribute__((ext_vector_type(4))) float;

__device__ __forceinline__ float bfu2f(u16 u) { return __builtin_bit_cast(float, (u32)u << 16); }
__device__ __forceinline__ u16   f2bfu(float f) {
  u32 u = __builtin_bit_cast(u32, f);
  return (u16)((u + 0x7fffu + ((u >> 16) & 1u)) >> 16);   // RNE
}
#define DIV14(x) (((x) * 4682) >> 16)   // exact floor(x/14) for 0<=x<256
#define WAIT_VM0()   __builtin_amdgcn_s_waitcnt(0x3f70)   // vmcnt(0)
#define WAIT_LGKM0() __builtin_amdgcn_s_waitcnt(0xc07f)   // lgkmcnt(0)

// async global->LDS, 16B per lane; LDS dest = wave-uniform base + lane*16
__device__ __forceinline__ void gld_lds16(const u16* g, u16* l) {
  __builtin_amdgcn_global_load_lds(
      (const __attribute__((address_space(1))) u32*)g,
      (__attribute__((address_space(3))) u32*)l, 16, 0, 0);
}

// ---------------------------------------------------------------------------
// dtype detector: FLAG=1 => bf16 tensors, FLAG=0 => fp32.
// ---------------------------------------------------------------------------
__global__ __launch_bounds__(256) void detect_k(const u16* __restrict__ x, int* __restrict__ flag)
{
  __shared__ int tot;
  if (threadIdx.x == 0) tot = 0;
  __syncthreads();
  int cnt = 0;
  for (int i = threadIdx.x; i < 4096; i += 256) {
    int e = (x[2 * i] >> 7) & 0xFF;
    cnt += (e >= 100 && e <= 134) ? 1 : 0;
  }
  atomicAdd(&tot, cnt);
  __syncthreads();
  if (threadIdx.x == 0) *flag = (tot >= 2458) ? 1 : 0;
}

// ---------------------------------------------------------------------------
// small-param conversion -> bf16 mirror
// ---------------------------------------------------------------------------
struct CvtEnt { const void* src; int n; int dstoff; };
struct CvtArgs { CvtEnt e[24]; int cnt; };

__global__ __launch_bounds__(256) void tobf_multi_k(CvtArgs a, u16* __restrict__ dst,
                                                    const int* __restrict__ flag)
{
  int gid = blockIdx.x * 256 + threadIdx.x;
  bool isbf = (*flag != 0);
  for (int t = 0; t < a.cnt; ++t)
    if (gid < a.e[t].n)
      dst[a.e[t].dstoff + gid] = isbf ? ((const u16*)a.e[t].src)[gid]
                                      : f2bfu(((const float*)a.e[t].src)[gid]);
}

__global__ __launch_bounds__(256) void tobf4_k(const void* __restrict__ src, u16* __restrict__ dst,
                                               int n4, const int* __restrict__ flag)
{
  int i = blockIdx.x * 256 + threadIdx.x;
  if (i >= n4) return;
  ushort4 o;
  if (*flag) o = ((const ushort4*)src)[i];
  else {
    float4 f = ((const float4*)src)[i];
    o.x = f2bfu(f.x); o.y = f2bfu(f.y); o.z = f2bfu(f.z); o.w = f2bfu(f.w);
  }
  ((ushort4*)dst)[i] = o;
}

// ---------------------------------------------------------------------------
// Weight convert + transpose: W[K][N] -> Wt[N][K] bf16. 64x64 LDS tiles.
// ---------------------------------------------------------------------------
__global__ __launch_bounds__(256) void tobfT_k(const void* __restrict__ src, u16* __restrict__ dst,
                                               int K, int N, const int* __restrict__ flag)
{
  __shared__ u16 t[64][65];
  const int n0 = blockIdx.x * 64, k0 = blockIdx.y * 64;
  const int r = threadIdx.x >> 2, c = (threadIdx.x & 3) * 16;
  if (*flag) {
    const u16* s = (const u16*)src + (size_t)(k0 + r) * N + n0 + c;
    union { uint4 v[2]; u16 e[16]; } u;
    u.v[0] = *(const uint4*)s; u.v[1] = *(const uint4*)(s + 8);
    #pragma unroll
    for (int j = 0; j < 16; ++j) t[c + j][r] = u.e[j];
  } else {
    const float* s = (const float*)src + (size_t)(k0 + r) * N + n0 + c;
    #pragma unroll
    for (int j = 0; j < 16; ++j) t[c + j][r] = f2bfu(s[j]);
  }
  __syncthreads();
  union { uint4 v[2]; u16 e[16]; } o;
  #pragma unroll
  for (int j = 0; j < 16; ++j) o.e[j] = t[r][c + j];
  u16* d = dst + (size_t)(n0 + r) * K + k0 + c;
  *(uint4*)d = o.v[0]; *(uint4*)(d + 8) = o.v[1];
}

// ---------------------------------------------------------------------------
// im2col for the 16x16/stride-16 patch embed
// ---------------------------------------------------------------------------
__global__ __launch_bounds__(256) void im2col_k(const void* __restrict__ xv, u16* __restrict__ a,
                                                const int* __restrict__ flag)
{
  int t = blockIdx.x, tid = threadIdx.x;
  int py = t >> 6, px = t & 63;
  int ky = tid >> 4, kx = tid & 15;
  size_t src = (size_t)(py * 16 + ky) * 1024 + px * 16 + kx;
  u16 v0, v1, v2;
  if (*flag) {
    const u16* x = (const u16*)xv;
    v0 = x[src]; v1 = x[src + 1048576]; v2 = x[src + 2097152];
  } else {
    const float* x = (const float*)xv;
    v0 = f2bfu(x[src]); v1 = f2bfu(x[src + 1048576]); v2 = f2bfu(x[src + 2097152]);
  }
  size_t dst = (size_t)t * 768 + tid * 3;
  a[dst] = v0; a[dst + 1] = v1; a[dst + 2] = v2;
}

// ---------------------------------------------------------------------------
// LayerNorm over C=768, f32 in -> bf16 out
// ---------------------------------------------------------------------------
__global__ __launch_bounds__(256) void ln_k(const float* __restrict__ x,
                                            const u16* __restrict__ g,
                                            const u16* __restrict__ b,
                                            u16* __restrict__ y)
{
  const int t = blockIdx.x, tid = threadIdx.x;
  const float* xp = x + (size_t)t * 768;
  float v0 = xp[tid], v1 = xp[tid + 256], v2 = xp[tid + 512];
  float s = v0 + v1 + v2;
  float q = v0 * v0 + v1 * v1 + v2 * v2;
  #pragma unroll
  for (int off = 32; off; off >>= 1) { s += __shfl_xor(s, off); q += __shfl_xor(q, off); }
  __shared__ float red[8];
  int wid = tid >> 6, lane = tid & 63;
  if (lane == 0) { red[wid] = s; red[4 + wid] = q; }
  __syncthreads();
  s = red[0] + red[1] + red[2] + red[3];
  q = red[4] + red[5] + red[6] + red[7];
  float mean = s * (1.f / 768.f);
  float var  = q * (1.f / 768.f) - mean * mean;
  float rstd = rsqrtf(var + 1e-5f);
  u16* yp = y + (size_t)t * 768;
  yp[tid]       = f2bfu((v0 - mean) * rstd * bfu2f(g[tid])       + bfu2f(b[tid]));
  yp[tid + 256] = f2bfu((v1 - mean) * rstd * bfu2f(g[tid + 256]) + bfu2f(b[tid + 256]));
  yp[tid + 512] = f2bfu((v2 - mean) * rstd * bfu2f(g[tid + 512]) + bfu2f(b[tid + 512]));
}

// ---------------------------------------------------------------------------
// Window partition 64x64 -> 25 windows of 14x14 zero-padded
// ---------------------------------------------------------------------------
__global__ __launch_bounds__(256) void win_part_k(const u16* __restrict__ ln, u16* __restrict__ w)
{
  int vid = blockIdx.x * 256 + threadIdx.x;
  if (vid >= 470400) return;
  size_t idx = (size_t)vid * 8;
  int c = (int)(idx % 768);
  int r = (int)(idx / 768);
  int win = r / 196, tok = r - win * 196;
  int gy = (win / 5) * 14 + tok / 14;
  int gx = (win % 5) * 14 + tok % 14;
  uint4 v = make_uint4(0, 0, 0, 0);
  if (gy < 64 && gx < 64)
    v = *(const uint4*)(ln + ((size_t)(gy * 64 + gx) * 768 + c));
  *(uint4*)(w + idx) = v;
}

// ---------------------------------------------------------------------------
// MFMA GEMM, double-buffered global_load_lds staging.
// C = A(MxK) * Bt(NxK)^T + bias, fused epilogues. 128xBN tile, BK=32.
// ---------------------------------------------------------------------------
enum { MODE_FEAT = 0, MODE_QKV = 1, MODE_RES = 2, MODE_GELU = 3, MODE_OUT = 4 };

template<int BN>
__global__ __launch_bounds__(256) void mgemm_k(
    const u16* __restrict__ A, const u16* __restrict__ Bt, const u16* __restrict__ bias,
    int M, int N, int K, int mode,
    float* __restrict__ outf, u16* __restrict__ outb,
    const float* __restrict__ res, const u16* __restrict__ pos,
    u16* __restrict__ qb, u16* __restrict__ kb, u16* __restrict__ vt, int TW,
    const int* __restrict__ flagp)
{
  constexpr int NWN = BN / 64, NWM = 4 / NWN;
  constexpr int WTM = 128 / NWM;            // 64 or 32
  constexpr int MS = WTM / 16, NS = 4;
  __shared__ __align__(16) u16 As[2][128 * 32];
  __shared__ __align__(16) u16 Bs[2][BN * 32];
  const int tid = threadIdx.x;
  const int wid = tid >> 6, lane = tid & 63;
  const int l15 = lane & 15, quad = lane >> 4;
  const int wm = wid / NWN, wn = wid % NWN;
  const int m0 = blockIdx.y * 128, n0 = blockIdx.x * BN;

  floatx4 acc[MS][NS];
  #pragma unroll
  for (int i = 0; i < MS; ++i)
    #pragma unroll
    for (int j = 0; j < NS; ++j) acc[i][j] = (floatx4){0.f, 0.f, 0.f, 0.f};

  // staging: per wave, 16 rows per DMA call (lane>>2), 8 u16/lane ((lane&3)*8)
  const int sr = lane >> 2, sc = (lane & 3) * 8;
  const u16* ag0 = A + (size_t)min(m0 + wid * 32 + sr,      M - 1) * K + sc;
  const u16* ag1 = A + (size_t)min(m0 + wid * 32 + 16 + sr, M - 1) * K + sc;
  const u16 *bg0 = nullptr, *bg1 = nullptr;
  if constexpr (BN == 128) {
    bg0 = Bt + (size_t)(n0 + wid * 32 + sr) * K + sc;
    bg1 = Bt + (size_t)(n0 + wid * 32 + 16 + sr) * K + sc;
  } else {
    bg0 = Bt + (size_t)(n0 + wid * 16 + sr) * K + sc;
  }

  auto issue = [&](int buf, int k0) {
    gld_lds16(ag0 + k0, &As[buf][(wid * 32) * 32]);
    gld_lds16(ag1 + k0, &As[buf][(wid * 32 + 16) * 32]);
    if constexpr (BN == 128) {
      gld_lds16(bg0 + k0, &Bs[buf][(wid * 32) * 32]);
      gld_lds16(bg1 + k0, &Bs[buf][(wid * 32 + 16) * 32]);
    } else {
      gld_lds16(bg0 + k0, &Bs[buf][(wid * 16) * 32]);
    }
  };

  issue(0, 0);
  int bufi = 0;
  for (int k0 = 0; k0 < K; k0 += 32, bufi ^= 1) {
    WAIT_VM0();                 // my DMA for buf bufi landed
    __syncthreads();            // all waves' DMA landed; prior compute done
    if (k0 + 32 < K) issue(bufi ^ 1, k0 + 32);   // next tile flies during MFMAs
    short8 af[MS], bf[NS];
    #pragma unroll
    for (int ms = 0; ms < MS; ++ms)
      af[ms] = *(const short8*)&As[bufi][(wm * WTM + ms * 16 + l15) * 32 + quad * 8];
    #pragma unroll
    for (int ns = 0; ns < NS; ++ns)
      bf[ns] = *(const short8*)&Bs[bufi][(wn * 64 + ns * 16 + l15) * 32 + quad * 8];
    #pragma unroll
    for (int ms = 0; ms < MS; ++ms)
      #pragma unroll
      for (int ns = 0; ns < NS; ++ns)
        acc[ms][ns] = __builtin_amdgcn_mfma_f32_16x16x32_bf16(af[ms], bf[ns], acc[ms][ns], 0, 0, 0);
  }

  const bool outbf = (mode == MODE_OUT) ? (*flagp != 0) : false;
  #pragma unroll
  for (int ms = 0; ms < MS; ++ms) {
    const int gmb = m0 + wm * WTM + ms * 16 + quad * 4;
    #pragma unroll
    for (int ns = 0; ns < NS; ++ns) {
      const int gn = n0 + wn * 64 + ns * 16 + l15;
      const float bb = bfu2f(bias[gn]);
      if (mode == MODE_QKV) {
        const int s = gn / 768, nn = gn - s * 768, h = nn >> 6, d = nn & 63;
        #pragma unroll
        for (int r = 0; r < 4; ++r) {
          int gm = gmb + r; if (gm >= M) continue;
          float v = acc[ms][ns][r] + bb;
          int b = gm / TW, tok = gm - b * TW;
          size_t bh = (size_t)(b * 12 + h);
          if (s == 0)      qb[(bh * TW + tok) * 64 + d] = f2bfu(v);
          else if (s == 1) kb[(bh * TW + tok) * 64 + d] = f2bfu(v);
          else             vt[(bh * 64 + d) * TW + tok] = f2bfu(v);
        }
      } else {
        #pragma unroll
        for (int r = 0; r < 4; ++r) {
          int gm = gmb + r; if (gm >= M) continue;
          size_t o = (size_t)gm * N + gn;
          float v = acc[ms][ns][r] + bb;
          if (mode == MODE_FEAT)      outf[o] = v + bfu2f(pos[o]);
          else if (mode == MODE_RES)  outf[o] = v + res[o];
          else if (mode == MODE_GELU) outb[o] = f2bfu(0.5f * v * (1.f + erff(v * 0.70710678f)));
          else {
            float ov = v + res[o];
            if (outbf) outb[o] = f2bfu(ov);
            else       outf[o] = ov;
          }
        }
      }
    }
  }
}

// ---------------------------------------------------------------------------
// MFMA flash attention.
// LDS regions (u16 idx, TS=72 padded): RQ (Q stage -> P), RK (K tile; !WIN GW
// scratch pre-loop), RV (V tile; rel staging pre-loop), RG (GH; +GW for WIN).
// Q fragment hoisted to VGPRs after staging. Global block: Gh is tile-constant
// per row (ky==kt) -> folded into the softmax shift; Gw hoisted to registers.
// ---------------------------------------------------------------------------
template<int NT, int TD, bool WIN>
__global__ __launch_bounds__(256) void flash_k(
    const u16* __restrict__ qb, const u16* __restrict__ kb, const u16* __restrict__ vt,
    const u16* __restrict__ relh, const u16* __restrict__ relw,
    u16* __restrict__ outb)
{
  constexpr int NTAB = 2 * TD - 1;
  constexpr int KT = (NT + 63) >> 6;
  constexpr int TS = 72;
  constexpr int RQ = 0;               // Q stage, then P
  constexpr int RK = 64 * TS;         // K tile; !WIN: GW scratch (stride 66)
  constexpr int RV = 2 * 64 * TS;     // V tile; rel-table staging pre-loop
  constexpr int RG = 3 * 64 * TS;     // GH
  constexpr int GHS = WIN ? 34 : 66;
  constexpr int GWWIN = RG + 64 * GHS;
  constexpr int TOT = WIN ? (GWWIN + 64 * 34) : (RG + 64 * GHS);
  __shared__ __align__(16) u16 lds[TOT];

  const int tid = threadIdx.x, wid = tid >> 6, lane = tid & 63;
  const int l15 = lane & 15, quad = lane >> 4;
  const int qt = blockIdx.x, bh = blockIdx.y;
  const int q0 = qt * 64;
  const size_t kvbase = (size_t)bh * NT * 64;
  const size_t vbase  = (size_t)bh * 64 * NT;

  // ---- stage Q tile, hoist fragment to VGPRs ----
  {
    const int r = tid >> 2, c = (tid & 3) << 4;
    const int tok = min(q0 + r, NT - 1);
    const uint4* p = (const uint4*)(qb + kvbase + (size_t)tok * 64 + c);
    *(uint4*)&lds[RQ + r * TS + c]     = p[0];
    *(uint4*)&lds[RQ + r * TS + c + 8] = p[1];
  }
  __syncthreads();
  short8 qf[2];
  qf[0] = *(const short8*)&lds[RQ + (wid * 16 + l15) * TS + quad * 8];
  qf[1] = *(const short8*)&lds[RQ + (wid * 16 + l15) * TS + 32 + quad * 8];
  WAIT_LGKM0();   // Q reads done before anything (later P writes) touch RQ

  auto stageRB = [&](const u16* tab, int rowoff, int maxrow) {
    const int r = tid >> 2, c = (tid & 3) << 4;
    const int tr = min(rowoff + r, maxrow);
    const uint4* p = (const uint4*)(tab + (size_t)tr * 64 + c);
    *(uint4*)&lds[RV + r * TS + c]     = p[0];
    *(uint4*)&lds[RV + r * TS + c + 8] = p[1];
  };
  auto gpass = [&](int gbase, int gstride, int ncols) {
    for (int ns = 0; ns < ncols / 16; ++ns) {
      floatx4 g = (floatx4){0.f, 0.f, 0.f, 0.f};
      #pragma unroll
      for (int ks = 0; ks < 2; ++ks) {
        short8 b = *(const short8*)&lds[RV + (ns * 16 + l15) * TS + ks * 32 + quad * 8];
        g = __builtin_amdgcn_mfma_f32_16x16x32_bf16(qf[ks], b, g, 0, 0, 0);
      }
      #pragma unroll
      for (int r = 0; r < 4; ++r)
        lds[gbase + (wid * 16 + quad * 4 + r) * gstride + ns * 16 + l15] = f2bfu(g[r]);
    }
  };

  float gwv[4][4];
  if constexpr (!WIN) {
    stageRB(relh, qt, NTAB - 1);  __syncthreads();
    gpass(RG, GHS, 64);                           // GH (wave-private rows)
    __syncthreads();                              // RV reads done -> restage ok
    stageRB(relw, 0, NTAB - 1);   __syncthreads();
    gpass(RK, 66, 64);                            // GW cols 0..63
    #pragma unroll
    for (int r = 0; r < 4; ++r) {
      const int tr = wid * 16 + quad * 4 + r;
      #pragma unroll
      for (int ns = 0; ns < 4; ++ns) {
        const int iw = tr - (ns * 16 + l15) + 63;
        if (iw < 64) gwv[ns][r] = bfu2f(lds[RK + tr * 66 + iw]);
      }
    }
    WAIT_LGKM0();
    __syncthreads();                              // RV reads done -> restage ok
    stageRB(relw, 64, NTAB - 1);  __syncthreads();
    gpass(RK, 66, 64);                            // GW cols 64..127 (stored 0..63)
    #pragma unroll
    for (int r = 0; r < 4; ++r) {
      const int tr = wid * 16 + quad * 4 + r;
      #pragma unroll
      for (int ns = 0; ns < 4; ++ns) {
        const int iw = tr - (ns * 16 + l15) + 63;
        if (iw >= 64) gwv[ns][r] = bfu2f(lds[RK + tr * 66 + iw - 64]);
      }
    }
    WAIT_LGKM0();   // GW reads done before k-loop restages RK
  } else {
    stageRB(relh, 0, NTAB - 1);  __syncthreads();
    gpass(RG, 34, 32);
    __syncthreads();
    stageRB(relw, 0, NTAB - 1);  __syncthreads();
    gpass(GWWIN, 34, 32);
  }

  // ---- online-softmax state ----
  float mI[4], lI[4];
  floatx4 Oacc[4];
  #pragma unroll
  for (int r = 0; r < 4; ++r) { mI[r] = -3e38f; lI[r] = 0.f; }
  #pragma unroll
  for (int d = 0; d < 4; ++d) Oacc[d] = (floatx4){0.f, 0.f, 0.f, 0.f};

  // ---- K loop ----
  for (int kt = 0; kt < KT; ++kt) {
    __syncthreads();            // prior tile's LDS reads done before restage
    {
      const int r = tid >> 2, c = (tid & 3) << 4;
      const int key = min(kt * 64 + r, NT - 1);
      const uint4* p = (const uint4*)(kb + kvbase + (size_t)key * 64 + c);
      *(uint4*)&lds[RK + r * TS + c]     = p[0];
      *(uint4*)&lds[RK + r * TS + c + 8] = p[1];
    }
    if constexpr (NT % 64 == 0) {
      const int d = tid >> 2, c = (tid & 3) << 4;
      const uint4* p = (const uint4*)(vt + vbase + (size_t)d * NT + kt * 64 + c);
      *(uint4*)&lds[RV + d * TS + c]     = p[0];
      *(uint4*)&lds[RV + d * TS + c + 8] = p[1];
    } else {
      const int d = tid >> 2, c = (tid & 3) << 4;
      #pragma unroll
      for (int j = 0; j < 16; ++j) {
        int key = min(kt * 64 + c + j, NT - 1);
        lds[RV + d * TS + c + j] = vt[vbase + (size_t)d * NT + key];
      }
    }
    __syncthreads();

    // QK^T (A = hoisted Q regs)
    floatx4 sacc[4];
    #pragma unroll
    for (int ns = 0; ns < 4; ++ns) sacc[ns] = (floatx4){0.f, 0.f, 0.f, 0.f};
    #pragma unroll
    for (int ks = 0; ks < 2; ++ks)
      #pragma unroll
      for (int ns = 0; ns < 4; ++ns) {
        short8 b = *(const short8*)&lds[RK + (ns * 16 + l15) * TS + ks * 32 + quad * 8];
        sacc[ns] = __builtin_amdgcn_mfma_f32_16x16x32_bf16(qf[ks], b, sacc[ns], 0, 0, 0);
      }

    // scale + rel bias
    float sv[4][4];
    #pragma unroll
    for (int r = 0; r < 4; ++r) {
      if constexpr (!WIN) {
        #pragma unroll
        for (int ns = 0; ns < 4; ++ns)
          sv[ns][r] = fmaf(0.125f, sacc[ns][r], gwv[ns][r]);   // Gh folded below
      } else {
        const int tr = wid * 16 + quad * 4 + r;
        const int tok = q0 + tr;
        const int qy = DIV14(tok), qx = tok - 14 * qy;
        #pragma unroll
        for (int ns = 0; ns < 4; ++ns) {
          const int j = kt * 64 + ns * 16 + l15;
          const int ky = DIV14(j), kx = j - 14 * ky;
          int ih = qy - ky + 13; ih = max(0, min(ih, 31));
          int iw = qx - kx + 13; iw = max(0, min(iw, 31));
          float s = 0.125f * sacc[ns][r] + bfu2f(lds[RG + tr * 34 + ih])
                                        + bfu2f(lds[GWWIN + tr * 34 + iw]);
          sv[ns][r] = (j < NT) ? s : -1e30f;
        }
      }
    }

    // online softmax (row lives across 16 lanes of a quad)
    #pragma unroll
    for (int r = 0; r < 4; ++r) {
      const int tr = wid * 16 + quad * 4 + r;
      float rm = fmaxf(fmaxf(sv[0][r], sv[1][r]), fmaxf(sv[2][r], sv[3][r]));
      #pragma unroll
      for (int off = 1; off < 16; off <<= 1) rm = fmaxf(rm, __shfl_xor(rm, off));
      float ghv = 0.f;
      if constexpr (!WIN) ghv = bfu2f(lds[RG + tr * GHS + (63 - kt)]);   // tile-const
      const float mt = rm + ghv;
      const float mn = fmaxf(mI[r], mt);
      const float al = __expf(mI[r] - mn);
      mI[r] = mn;
      const float t = mn - ghv;
      float rs = 0.f;
      #pragma unroll
      for (int ns = 0; ns < 4; ++ns) {
        float p = __expf(sv[ns][r] - t);
        rs += p;
        lds[RQ + tr * TS + ns * 16 + l15] = f2bfu(p);   // P aliases Q region
      }
      #pragma unroll
      for (int off = 1; off < 16; off <<= 1) rs += __shfl_xor(rs, off);
      lI[r] = lI[r] * al + rs;
      #pragma unroll
      for (int d = 0; d < 4; ++d) Oacc[d][r] *= al;
    }

    // PV
    #pragma unroll
    for (int ks = 0; ks < 2; ++ks) {
      short8 a = *(const short8*)&lds[RQ + (wid * 16 + l15) * TS + ks * 32 + quad * 8];
      #pragma unroll
      for (int d = 0; d < 4; ++d) {
        short8 b = *(const short8*)&lds[RV + (d * 16 + l15) * TS + ks * 32 + quad * 8];
        Oacc[d] = __builtin_amdgcn_mfma_f32_16x16x32_bf16(a, b, Oacc[d], 0, 0, 0);
      }
    }
  }

  // ---- output ----
  #pragma unroll
  for (int r = 0; r < 4; ++r) {
    const int tr = wid * 16 + quad * 4 + r;
    const float rinv = 1.f / lI[r];
    const int tok = q0 + tr;
    if constexpr (WIN) {
      if (tok >= NT) continue;
      const int win = bh / 12, h = bh - win * 12;
      const int ty = DIV14(tok), tx = tok - 14 * ty;
      const int gy = (win / 5) * 14 + ty, gx = (win % 5) * 14 + tx;
      if (gy >= 64 || gx >= 64) continue;
      u16* op = outb + (size_t)(gy * 64 + gx) * 768 + h * 64;
      #pragma unroll
      for (int d = 0; d < 4; ++d) op[d * 16 + l15] = f2bfu(Oacc[d][r] * rinv);
    } else {
      u16* op = outb + (size_t)tok * 768 + bh * 64;
      #pragma unroll
      for (int d = 0; d < 4; ++d) op[d * 16 + l15] = f2bfu(Oacc[d][r] * rinv);
    }
  }
}

// ---------------------------------------------------------------------------
extern "C" void kernel_launch(void* const* d_in, const int* in_sizes, int n_in,
                              void* d_out, int out_size, void* d_ws, size_t ws_size,
                              hipStream_t stream)
{
  const void* x      = d_in[0];
  const void* patchw = d_in[1];
  const void* patchb = d_in[2];
  const void* pos    = d_in[3];
  const void *ln1g1 = d_in[4],  *ln1b1 = d_in[5];
  const void *qkvw1 = d_in[6],  *qkvb1 = d_in[7];
  const void *projw1= d_in[8],  *projb1= d_in[9];
  const void *relh1 = d_in[10], *relw1 = d_in[11];
  const void *ln2g1 = d_in[12], *ln2b1 = d_in[13];
  const void *mw11  = d_in[14], *mb11  = d_in[15];
  const void *mw21  = d_in[16], *mb21  = d_in[17];
  const void *ln1g2 = d_in[18], *ln1b2 = d_in[19];
  const void *qkvw2 = d_in[20], *qkvb2 = d_in[21];
  const void *projw2= d_in[22], *projb2= d_in[23];
  const void *relh2 = d_in[24], *relw2 = d_in[25];
  const void *ln2g2 = d_in[26], *ln2b2 = d_in[27];
  const void *mw12  = d_in[28], *mb12  = d_in[29];
  const void *mw22  = d_in[30], *mb22  = d_in[31];

  char* w = (char*)d_ws;
  int*   FLAG = (int*)w;  w += 64;
  float* R0 = (float*)w;  w += 12582912;
  float* R1 = (float*)w;  w += 12582912;
  u16*   B0 = (u16*)w;    w += 6291456;
  u16*   Wb = (u16*)w;    w += 7526400;
  u16*   QB = (u16*)w;    w += 7526400;   // [bh][tok][64]
  u16*   KB = (u16*)w;    w += 7526400;   // [bh][tok][64]
  u16*   VT = (u16*)w;    w += 7526400;   // [bh][d][tok]
  u16*   Hb = (u16*)w;    w += 25165824;
  u16*   WA = (u16*)w;    w += 14155776;  // transposed weight arena
  u16*   POSb = (u16*)w;  w += 6291456;
  u16*   PRM = (u16*)w;   w += 106560;
  u16*   Ap = Hb;

  constexpr int WA_QKV = 0, WA_PROJ = 1769472, WA_M1 = 2359296, WA_M2 = 4718592;
  constexpr int PRM_PATCHB = 0, PB1 = 768, PBLK = 26240, PB2 = 768 + PBLK;
  constexpr int O_QKVB = 0, O_PROJB = 2304, O_MB1 = 3072, O_MB2 = 6144,
                O_LN1G = 6912, O_LN1B = 7680, O_LN2G = 8448, O_LN2B = 9216,
                O_RELH = 9984, O_RELW = 18112;

  detect_k<<<1, 256, 0, stream>>>((const u16*)x, FLAG);
  CvtArgs ca; int kk = 0;
  auto add = [&](const void* s, int n, int off) { ca.e[kk].src = s; ca.e[kk].n = n; ca.e[kk].dstoff = off; ++kk; };
  add(patchb, 768, PRM_PATCHB);
  add(qkvb1, 2304, PB1 + O_QKVB); add(projb1, 768, PB1 + O_PROJB);
  add(mb11, 3072, PB1 + O_MB1);   add(mb21, 768, PB1 + O_MB2);
  add(ln1g1, 768, PB1 + O_LN1G);  add(ln1b1, 768, PB1 + O_LN1B);
  add(ln2g1, 768, PB1 + O_LN2G);  add(ln2b1, 768, PB1 + O_LN2B);
  add(relh1, 27 * 64, PB1 + O_RELH); add(relw1, 27 * 64, PB1 + O_RELW);
  add(qkvb2, 2304, PB2 + O_QKVB); add(projb2, 768, PB2 + O_PROJB);
  add(mb12, 3072, PB2 + O_MB1);   add(mb22, 768, PB2 + O_MB2);
  add(ln1g2, 768, PB2 + O_LN1G);  add(ln1b2, 768, PB2 + O_LN1B);
  add(ln2g2, 768, PB2 + O_LN2G);  add(ln2b2, 768, PB2 + O_LN2B);
  add(relh2, 127 * 64, PB2 + O_RELH); add(relw2, 127 * 64, PB2 + O_RELW);
  ca.cnt = kk;
  tobf_multi_k<<<32, 256, 0, stream>>>(ca, PRM, FLAG);
  tobf4_k<<<3072, 256, 0, stream>>>(pos, POSb, 786432, FLAG);

  // ---- patch embed ----
  tobfT_k<<<dim3(12, 12), 256, 0, stream>>>(patchw, WA + WA_M1, 768, 768, FLAG);
  im2col_k<<<4096, 256, 0, stream>>>(x, Ap, FLAG);
  mgemm_k<64><<<dim3(12, 32), 256, 0, stream>>>(Ap, WA + WA_M1, PRM + PRM_PATCHB,
      4096, 768, 768, MODE_FEAT, R0, nullptr, nullptr, POSb, nullptr, nullptr, nullptr, 0, FLAG);

  // ---- block 1 weights ----
  tobfT_k<<<dim3(36, 12), 256, 0, stream>>>(qkvw1, WA + WA_QKV, 768, 2304, FLAG);
  tobfT_k<<<dim3(12, 12), 256, 0, stream>>>(projw1, WA + WA_PROJ, 768, 768, FLAG);
  tobfT_k<<<dim3(48, 12), 256, 0, stream>>>(mw11, WA + WA_M1, 768, 3072, FLAG);
  tobfT_k<<<dim3(12, 48), 256, 0, stream>>>(mw21, WA + WA_M2, 3072, 768, FLAG);

  // ---- block 1 (windowed) ----
  ln_k<<<4096, 256, 0, stream>>>(R0, PRM + PB1 + O_LN1G, PRM + PB1 + O_LN1B, B0);
  win_part_k<<<1838, 256, 0, stream>>>(B0, Wb);
  mgemm_k<128><<<dim3(18, 39), 256, 0, stream>>>(Wb, WA + WA_QKV, PRM + PB1 + O_QKVB,
      4900, 2304, 768, MODE_QKV, nullptr, nullptr, nullptr, nullptr, QB, KB, VT, 196, FLAG);
  flash_k<196, 14, true><<<dim3(4, 300), 256, 0, stream>>>(QB, KB, VT,
      PRM + PB1 + O_RELH, PRM + PB1 + O_RELW, B0);
  mgemm_k<64><<<dim3(12, 32), 256, 0, stream>>>(B0, WA + WA_PROJ, PRM + PB1 + O_PROJB,
      4096, 768, 768, MODE_RES, R1, nullptr, R0, nullptr, nullptr, nullptr, nullptr, 0, FLAG);
  ln_k<<<4096, 256, 0, stream>>>(R1, PRM + PB1 + O_LN2G, PRM + PB1 + O_LN2B, B0);
  mgemm_k<128><<<dim3(24, 32), 256, 0, stream>>>(B0, WA + WA_M1, PRM + PB1 + O_MB1,
      4096, 3072, 768, MODE_GELU, nullptr, Hb, nullptr, nullptr, nullptr, nullptr, nullptr, 0, FLAG);
  mgemm_k<64><<<dim3(12, 32), 256, 0, stream>>>(Hb, WA + WA_M2, PRM + PB1 + O_MB2,
      4096, 768, 3072, MODE_RES, R0, nullptr, R1, nullptr, nullptr, nullptr, nullptr, 0, FLAG);

  // ---- block 2 weights ----
  tobfT_k<<<dim3(36, 12), 256, 0, stream>>>(qkvw2, WA + WA_QKV, 768, 2304, FLAG);
  tobfT_k<<<dim3(12, 12), 256, 0, stream>>>(projw2, WA + WA_PROJ, 768, 768, FLAG);
  tobfT_k<<<dim3(48, 12), 256, 0, stream>>>(mw12, WA + WA_M1, 768, 3072, FLAG);
  tobfT_k<<<dim3(12, 48), 256, 0, stream>>>(mw22, WA + WA_M2, 3072, 768, FLAG);

  // ---- block 2 (global) ----
  ln_k<<<4096, 256, 0, stream>>>(R0, PRM + PB2 + O_LN1G, PRM + PB2 + O_LN1B, B0);
  mgemm_k<128><<<dim3(18, 32), 256, 0, stream>>>(B0, WA + WA_QKV, PRM + PB2 + O_QKVB,
      4096, 2304, 768, MODE_QKV, nullptr, nullptr, nullptr, nullptr, QB, KB, VT, 4096, FLAG);
  flash_k<4096, 64, false><<<dim3(64, 12), 256, 0, stream>>>(QB, KB, VT,
      PRM + PB2 + O_RELH, PRM + PB2 + O_RELW, B0);
  mgemm_k<64><<<dim3(12, 32), 256, 0, stream>>>(B0, WA + WA_PROJ, PRM + PB2 + O_PROJB,
      4096, 768, 768, MODE_RES, R1, nullptr, R0, nullptr, nullptr, nullptr, nullptr, 0, FLAG);
  ln_k<<<4096, 256, 0, stream>>>(R1, PRM + PB2 + O_LN2G, PRM + PB2 + O_LN2B, B0);
  mgemm_k<128><<<dim3(24, 32), 256, 0, stream>>>(B0, WA + WA_M1, PRM + PB2 + O_MB1,
      4096, 3072, 768, MODE_GELU, nullptr, Hb, nullptr, nullptr, nullptr, nullptr, nullptr, 0, FLAG);
  mgemm_k<64><<<dim3(12, 32), 256, 0, stream>>>(Hb, WA + WA_M2, PRM + PB2 + O_MB2,
      4096, 768, 3072, MODE_OUT, (float*)d_out, (u16*)d_out, R1, nullptr, nullptr, nullptr, nullptr, 0, FLAG);
}